// Round 15
// baseline (6510.769 us; speedup 1.0000x reference)
//
#include <hip/hip_runtime.h>
#include <cstdint>
#include <cstddef>

#define SEQ 4096
#define HID 512
#define NTHETA 5
#define NBLK 4
#define RPB 128                 // rows per block
#define SENT_BITS 0x40000000u   // 2.0f — |tanh| < 1, so never a real h value

typedef unsigned long long u64;

__device__ __forceinline__ float tanh_fast(float x) {
  x = fminf(fmaxf(x, -20.0f), 20.0f);
  const float e = __expf(2.0f * x);
  return (e - 1.0f) / (e + 1.0f);
}

// Opaque-value anchor: breaks the value's provenance chain to its load so the
// register allocator CANNOT rematerialize it from memory inside the t-loop
// (r13/r14 counters: VGPR=48 with 64 W floats declared -> W was re-loaded
// from L2 every step, after the poll, on the critical path). Scalar "+v"
// ties are supported (the r11 failure was 128-bit ties only).
#define KEEP4(a) \
  asm volatile("" : "+v"(a.x), "+v"(a.y), "+v"(a.z), "+v"(a.w))

// 16B poll load, agent-visible (sc1 path verified working at full speed, r10).
// Wait is INSIDE the asm (no in-flight writebacks across exits — r12 lesson).
// "memory" clobber RETAINED: it pins the step-t publish before the step-t+1
// spin (removing it would license the compiler to sink the publish past the
// next spin -> cross-block deadlock risk).
__device__ __forceinline__ uint4 load_x4_sc1(const unsigned* p) {
  uint4 u;
  asm volatile("global_load_dwordx4 %0, %1, off sc1\n\ts_waitcnt vmcnt(0)"
               : "=v"(u) : "v"(p) : "memory");
  return u;
}

// Butterfly sum over 16-lane groups: xor1, xor2, xor8 on the VALU (DPP),
// only xor4 on the DS pipe (ds_swizzle). Verified r9/r10.
__device__ __forceinline__ float red16(float v) {
  int p;
  p = __builtin_amdgcn_update_dpp(0, __float_as_int(v), 0xB1, 0xF, 0xF, true);  // ^1
  v += __int_as_float(p);
  p = __builtin_amdgcn_update_dpp(0, __float_as_int(v), 0x4E, 0xF, 0xF, true);  // ^2
  v += __int_as_float(p);
  v += __int_as_float(__builtin_amdgcn_ds_swizzle(__float_as_int(v), 0x101F)); // ^4
  p = __builtin_amdgcn_update_dpp(0, __float_as_int(v), 0x128, 0xF, 0xF, true); // row_ror:8 = ^8
  v += __int_as_float(p);
  return v;
}

// f4-chunk swizzle (<=2-way b128 reads, conflict-free b128 poll writes)
__device__ __forceinline__ int swz(int f) {
  return (f & ~7) | ((f ^ (f >> 3)) & 7);
}

// Shared poll routine (proven r10/r13): sequential sc1-x4 spin with every-8th
// scalar agent-atomic backstop.
__device__ __forceinline__ uint4 poll_chunk(const unsigned* src) {
  uint4 u = load_x4_sc1(src);
  int it = 0;
  while (u.x == SENT_BITS || u.y == SENT_BITS ||
         u.z == SENT_BITS || u.w == SENT_BITS) {
    if ((++it & 7) == 0) {
      u.x = __hip_atomic_load(src + 0, __ATOMIC_RELAXED,
                              __HIP_MEMORY_SCOPE_AGENT);
      u.y = __hip_atomic_load(src + 1, __ATOMIC_RELAXED,
                              __HIP_MEMORY_SCOPE_AGENT);
      u.z = __hip_atomic_load(src + 2, __ATOMIC_RELAXED,
                              __HIP_MEMORY_SCOPE_AGENT);
      u.w = __hip_atomic_load(src + 3, __ATOMIC_RELAXED,
                              __HIP_MEMORY_SCOPE_AGENT);
    } else {
      u = load_x4_sc1(src);
    }
  }
  return u;
}

// C[4096,512] = act(A[4096,K] @ W[512,K]^T + bias + noise_plane)
__global__ __launch_bounds__(256) void gemm_bias_noise(
    const float* __restrict__ A, const float* __restrict__ W,
    const float* __restrict__ bias, const float* __restrict__ noise,
    float* __restrict__ C, int K, int doTanh)
{
  const int N = HID;
  const int bm = blockIdx.y, bn = blockIdx.x;
  const int tid = threadIdx.x;
  const int tx = tid & 15, ty = tid >> 4;
  const int row0 = bm * 64, col0 = bn * 64;
  __shared__ float As[16][68];
  __shared__ float Ws[16][68];
  float acc[4][4] = {{0.f, 0.f, 0.f, 0.f}, {0.f, 0.f, 0.f, 0.f},
                     {0.f, 0.f, 0.f, 0.f}, {0.f, 0.f, 0.f, 0.f}};
  const int lrow = tid >> 2, lkq = tid & 3;
  for (int kt = 0; kt < K; kt += 16) {
    const float4 av = *(const float4*)&A[(size_t)(row0 + lrow) * K + kt + lkq * 4];
    const float4 wv = *(const float4*)&W[(size_t)(col0 + lrow) * K + kt + lkq * 4];
    __syncthreads();
    As[lkq * 4 + 0][lrow] = av.x; As[lkq * 4 + 1][lrow] = av.y;
    As[lkq * 4 + 2][lrow] = av.z; As[lkq * 4 + 3][lrow] = av.w;
    Ws[lkq * 4 + 0][lrow] = wv.x; Ws[lkq * 4 + 1][lrow] = wv.y;
    Ws[lkq * 4 + 2][lrow] = wv.z; Ws[lkq * 4 + 3][lrow] = wv.w;
    __syncthreads();
#pragma unroll
    for (int k = 0; k < 16; ++k) {
      const float4 a = *(const float4*)&As[k][ty * 4];
      const float4 bq = *(const float4*)&Ws[k][tx * 4];
      const float a4[4] = {a.x, a.y, a.z, a.w};
      const float b4[4] = {bq.x, bq.y, bq.z, bq.w};
#pragma unroll
      for (int i = 0; i < 4; ++i)
#pragma unroll
        for (int j = 0; j < 4; ++j)
          acc[i][j] = fmaf(a4[i], b4[j], acc[i][j]);
    }
  }
  const float4 bv = *(const float4*)&bias[col0 + tx * 4];
#pragma unroll
  for (int i = 0; i < 4; ++i) {
    const int row = row0 + ty * 4 + i;
    const float4 nv = *(const float4*)&noise[(size_t)row * N + col0 + tx * 4];
    float4 o;
    o.x = acc[i][0] + bv.x + nv.x;
    o.y = acc[i][1] + bv.y + nv.y;
    o.z = acc[i][2] + bv.z + nv.z;
    o.w = acc[i][3] + bv.w + nv.w;
    if (doTanh) {
      o.x = tanh_fast(o.x); o.y = tanh_fast(o.y);
      o.z = tanh_fast(o.z); o.w = tanh_fast(o.w);
    }
    *(float4*)&C[(size_t)row * N + col0 + tx * 4] = o;
  }
}

// Pre-fill the h-exchange buffer (= out plane 0) with the sentinel bits.
__global__ void fill_sentinel(uint4* __restrict__ p, int n4) {
  const int i = blockIdx.x * blockDim.x + threadIdx.x;
  if (i < n4) p[i] = make_uint4(SENT_BITS, SENT_BITS, SENT_BITS, SENT_BITS);
}

// Sequential scan h_t = tanh(drive_t + W_hh @ h_{t-1}).
// 4 blocks x 1024 thr; block owns 128 rows. Thread (i=tid>>4, j=tid&15)
// owns rows r0=base+2i, r0+1, cols 32j..+31 — 16 float4 W regs made
// GENUINELY register-resident via KEEP4 anchors (breaks remat provenance).
// Per step:
//   - DUAL-PHASE pollers: primary tid<96 and secondary tid in [512,608)
//     (different waves -> independent phase drift) spin on the same remote
//     16B chunks; whoever detects writes the same swizzled LDS slot with the
//     same value (benign race). Sampling-phase term ~halves.
//   - ONE barrier; 8 swizzled ds_read_b128 -> 64 FMA -> 2x red16.
//   - j==0: 2x tanh, ONE u64 agent publish, seed own float2 into next buffer.
__global__ __launch_bounds__(1024, 4) void recurrence(
    const float* __restrict__ Whh, const float* __restrict__ drive,
    const float* __restrict__ h0, unsigned* __restrict__ hexch)
{
  const int blk = blockIdx.x;
  const int base = blk * RPB;
  const int tid = threadIdx.x;
  const int i = tid >> 4;        // 0..63
  const int j = tid & 15;        // 0..15
  const int r0 = base + 2 * i;   // first of this thread's two rows

  __shared__ __align__(16) float hbuf[2][HID];

  // W: 2 rows x 32 cols -> 16 float4 regs, anchored opaque (no remat)
  float4 w0[8], w1[8];
#pragma unroll
  for (int c = 0; c < 8; ++c) {
    w0[c] = *(const float4*)&Whh[(size_t)r0 * HID + 32 * j + 4 * c];
    w1[c] = *(const float4*)&Whh[(size_t)(r0 + 1) * HID + 32 * j + 4 * c];
  }
#pragma unroll
  for (int c = 0; c < 8; ++c) { KEEP4(w0[c]); KEEP4(w1[c]); }

  // poller mapping: primary tid<96; secondary tid in [512,608) same chunks
  const bool poll1 = (tid < 96);
  const bool poll2 = (tid >= 512 && tid < 608);
  const int q = poll2 ? (tid - 512) : tid;            // 0..95 for pollers
  const int ch = (q < blk * 32) ? q : q + 32;         // skip own 32 chunks
  const int wslot = swz(ch);
  // own-seed slot (j==0): rows r0,r0+1 -> chunk r0>>2, offset r0&3 (0 or 2)
  const int z0 = swz(r0 >> 2) * 4 + (r0 & 3);

  // t=0 seed from h0
  if (tid < HID) hbuf[0][swz(tid >> 2) * 4 + (tid & 3)] = h0[tid];

  for (int t = 0; t < SEQ; ++t) {
    const int buf = t & 1;

    float2 dr = make_float2(0.f, 0.f);
    if (j == 0) dr = *(const float2*)&drive[(size_t)t * HID + r0];

    if (t > 0 && (poll1 || poll2)) {
      const unsigned* src = &hexch[(size_t)(t - 1) * HID + 4 * ch];
      const uint4 u = poll_chunk(src);
      ((uint4*)hbuf[buf])[wslot] = u;   // same value from both phases: benign
    }
    __syncthreads();   // buf ready; skew <= 1 step => other buffer safe
    asm volatile("" :: "v"(dr.x), "v"(dr.y));   // drv resident by now

    float a00 = 0.f, a01 = 0.f, a02 = 0.f, a03 = 0.f;
    float a10 = 0.f, a11 = 0.f, a12 = 0.f, a13 = 0.f;
#pragma unroll
    for (int c = 0; c < 8; ++c) {
      const float4 h4 = *(const float4*)&hbuf[buf][(8 * j + ((c ^ j) & 7)) * 4];
      a00 = fmaf(w0[c].x, h4.x, a00);
      a01 = fmaf(w0[c].y, h4.y, a01);
      a02 = fmaf(w0[c].z, h4.z, a02);
      a03 = fmaf(w0[c].w, h4.w, a03);
      a10 = fmaf(w1[c].x, h4.x, a10);
      a11 = fmaf(w1[c].y, h4.y, a11);
      a12 = fmaf(w1[c].z, h4.z, a12);
      a13 = fmaf(w1[c].w, h4.w, a13);
    }
    float s0 = red16((a00 + a01) + (a02 + a03));
    float s1 = red16((a10 + a11) + (a12 + a13));

    if (j == 0) {
      const float y0 = tanh_fast(s0 + dr.x);
      const float y1 = tanh_fast(s1 + dr.y);
      const u64 pk = (u64)__float_as_uint(y0) | ((u64)__float_as_uint(y1) << 32);
      // ONE u64 agent publish (r8-proven primitive); lanes 0/16/32/48 of a
      // wave coalesce into one contiguous 32B transaction.
      __hip_atomic_store((u64*)&hexch[(size_t)t * HID + r0], pk,
                         __ATOMIC_RELAXED, __HIP_MEMORY_SCOPE_AGENT);
      // own rows never leave the CU: seed next LDS buffer directly.
      *(float2*)&hbuf[buf ^ 1][z0] = make_float2(y0, y1);
    }
  }
}

__global__ void copy_final(const float* __restrict__ src, float* __restrict__ dst) {
  dst[threadIdx.x] = src[threadIdx.x];
}

extern "C" void kernel_launch(void* const* d_in, const int* in_sizes, int n_in,
                              void* d_out, int out_size, void* d_ws, size_t ws_size,
                              hipStream_t stream) {
  const float* input    = (const float*)d_in[0];
  const float* internal = (const float*)d_in[1];
  const float* state    = (const float*)d_in[2];
  const float* W_ih     = (const float*)d_in[3];
  const float* W_hh     = (const float*)d_in[4];
  const float* bias     = (const float*)d_in[5];
  float* out = (float*)d_out;

  const size_t plane = (size_t)SEQ * HID;
  // hexch IS out plane 0 (hs): prefilled with sentinel, every element
  // overwritten exactly once by the recurrence.
  unsigned* hexch = (unsigned*)out;
  float*    drive = out + 5 * plane;   // rewritten by theta-GEMM k=4 afterwards

  fill_sentinel<<<(SEQ * HID / 4 + 255) / 256, 256, 0, stream>>>(
      (uint4*)hexch, SEQ * HID / 4);

  dim3 gg(HID / 64, SEQ / 64);
  // drive = x @ W_ih^T + b + internal[0]   (no tanh)
  gemm_bias_noise<<<gg, 256, 0, stream>>>(input, W_ih, bias, internal, drive,
                                          HID, 0);
  // hs (out plane 0, via sentinel exchange)
  recurrence<<<NBLK, 1024, 0, stream>>>(W_hh, drive, state, hexch);
  // theta rollouts: plane k -> plane k+1
  for (int k = 0; k < NTHETA; ++k) {
    gemm_bias_noise<<<gg, 256, 0, stream>>>(out + (size_t)k * plane, W_hh, bias,
                                            internal + (size_t)(k + 1) * plane,
                                            out + (size_t)(k + 1) * plane,
                                            HID, 1);
  }
  // final_state = hs[4095]
  copy_final<<<1, HID, 0, stream>>>(out + (size_t)4095 * HID, out + 6 * plane);
}

// Round 16
// 6196.617 us; speedup vs baseline: 1.0507x; 1.0507x over previous
//
#include <hip/hip_runtime.h>
#include <cstdint>
#include <cstddef>

#define SEQ 4096
#define HID 512
#define NTHETA 5
#define NBLK 8
#define RPB 64                  // rows per block
#define NMAIL 4                 // mailbox planes (out planes 1..4)
#define SENT_BITS 0x40000000u   // 2.0f — |tanh| < 1, so never a real h value

typedef unsigned long long u64;

__device__ __forceinline__ float tanh_fast(float x) {
  x = fminf(fmaxf(x, -20.0f), 20.0f);
  const float e = __expf(2.0f * x);
  return (e - 1.0f) / (e + 1.0f);
}

// 16B poll load, agent-visible (sc1 path verified at full speed, r10).
// Wait INSIDE the asm: nothing in flight across exits (r12 lesson).
__device__ __forceinline__ uint4 load_x4_sc1(const unsigned* p) {
  uint4 u;
  asm volatile("global_load_dwordx4 %0, %1, off sc1\n\ts_waitcnt vmcnt(0)"
               : "=v"(u) : "v"(p) : "memory");
  return u;
}

__device__ __forceinline__ bool has_sent(uint4 u) {
  return u.x == SENT_BITS || u.y == SENT_BITS ||
         u.z == SENT_BITS || u.w == SENT_BITS;
}

// Poll a private-mailbox chunk; every 8th spin uses scalar agent-atomic loads
// (r2-proven); after ~4096 spins fall back to plane0 (canonical copy, always
// written) -> termination guaranteed even if the mailbox path is broken.
__device__ __forceinline__ uint4 poll_chunk(const unsigned* src,
                                            const unsigned* safe) {
  uint4 u = load_x4_sc1(src);
  int it = 0;
  while (has_sent(u)) {
    ++it;
    if ((it & 7) == 0) {
      const unsigned* s = (it >= 4096) ? safe : src;
      u.x = __hip_atomic_load(s + 0, __ATOMIC_RELAXED, __HIP_MEMORY_SCOPE_AGENT);
      u.y = __hip_atomic_load(s + 1, __ATOMIC_RELAXED, __HIP_MEMORY_SCOPE_AGENT);
      u.z = __hip_atomic_load(s + 2, __ATOMIC_RELAXED, __HIP_MEMORY_SCOPE_AGENT);
      u.w = __hip_atomic_load(s + 3, __ATOMIC_RELAXED, __HIP_MEMORY_SCOPE_AGENT);
    } else {
      u = load_x4_sc1(src);
    }
  }
  return u;
}

// Butterfly sum over 16-lane groups: xor1, xor2, xor8 on the VALU (DPP),
// only xor4 on the DS pipe (ds_swizzle). Verified r9/r10.
__device__ __forceinline__ float red16(float v) {
  int p;
  p = __builtin_amdgcn_update_dpp(0, __float_as_int(v), 0xB1, 0xF, 0xF, true);  // ^1
  v += __int_as_float(p);
  p = __builtin_amdgcn_update_dpp(0, __float_as_int(v), 0x4E, 0xF, 0xF, true);  // ^2
  v += __int_as_float(p);
  v += __int_as_float(__builtin_amdgcn_ds_swizzle(__float_as_int(v), 0x101F)); // ^4
  p = __builtin_amdgcn_update_dpp(0, __float_as_int(v), 0x128, 0xF, 0xF, true); // row_ror:8 = ^8
  v += __int_as_float(p);
  return v;
}

// f4-chunk swizzle (<=2-way b128 reads, conflict-free b128 poll writes)
__device__ __forceinline__ int swz(int f) {
  return (f & ~7) | ((f ^ (f >> 3)) & 7);
}

// C[4096,512] = act(A[4096,K] @ W[512,K]^T + bias + noise_plane)
__global__ __launch_bounds__(256) void gemm_bias_noise(
    const float* __restrict__ A, const float* __restrict__ W,
    const float* __restrict__ bias, const float* __restrict__ noise,
    float* __restrict__ C, int K, int doTanh)
{
  const int N = HID;
  const int bm = blockIdx.y, bn = blockIdx.x;
  const int tid = threadIdx.x;
  const int tx = tid & 15, ty = tid >> 4;
  const int row0 = bm * 64, col0 = bn * 64;
  __shared__ float As[16][68];
  __shared__ float Ws[16][68];
  float acc[4][4] = {{0.f, 0.f, 0.f, 0.f}, {0.f, 0.f, 0.f, 0.f},
                     {0.f, 0.f, 0.f, 0.f}, {0.f, 0.f, 0.f, 0.f}};
  const int lrow = tid >> 2, lkq = tid & 3;
  for (int kt = 0; kt < K; kt += 16) {
    const float4 av = *(const float4*)&A[(size_t)(row0 + lrow) * K + kt + lkq * 4];
    const float4 wv = *(const float4*)&W[(size_t)(col0 + lrow) * K + kt + lkq * 4];
    __syncthreads();
    As[lkq * 4 + 0][lrow] = av.x; As[lkq * 4 + 1][lrow] = av.y;
    As[lkq * 4 + 2][lrow] = av.z; As[lkq * 4 + 3][lrow] = av.w;
    Ws[lkq * 4 + 0][lrow] = wv.x; Ws[lkq * 4 + 1][lrow] = wv.y;
    Ws[lkq * 4 + 2][lrow] = wv.z; Ws[lkq * 4 + 3][lrow] = wv.w;
    __syncthreads();
#pragma unroll
    for (int k = 0; k < 16; ++k) {
      const float4 a = *(const float4*)&As[k][ty * 4];
      const float4 bq = *(const float4*)&Ws[k][tx * 4];
      const float a4[4] = {a.x, a.y, a.z, a.w};
      const float b4[4] = {bq.x, bq.y, bq.z, bq.w};
#pragma unroll
      for (int i = 0; i < 4; ++i)
#pragma unroll
        for (int j = 0; j < 4; ++j)
          acc[i][j] = fmaf(a4[i], b4[j], acc[i][j]);
    }
  }
  const float4 bv = *(const float4*)&bias[col0 + tx * 4];
#pragma unroll
  for (int i = 0; i < 4; ++i) {
    const int row = row0 + ty * 4 + i;
    const float4 nv = *(const float4*)&noise[(size_t)row * N + col0 + tx * 4];
    float4 o;
    o.x = acc[i][0] + bv.x + nv.x;
    o.y = acc[i][1] + bv.y + nv.y;
    o.z = acc[i][2] + bv.z + nv.z;
    o.w = acc[i][3] + bv.w + nv.w;
    if (doTanh) {
      o.x = tanh_fast(o.x); o.y = tanh_fast(o.y);
      o.z = tanh_fast(o.z); o.w = tanh_fast(o.w);
    }
    *(float4*)&C[(size_t)row * N + col0 + tx * 4] = o;
  }
}

// Pre-fill planes 0..4 (output/hs + 4 mailboxes) with the sentinel bits.
__global__ void fill_sentinel(uint4* __restrict__ p, int n4) {
  const int i = blockIdx.x * blockDim.x + threadIdx.x;
  if (i < n4) p[i] = make_uint4(SENT_BITS, SENT_BITS, SENT_BITS, SENT_BITS);
}

// Sequential scan h_t = tanh(drive_t + W_hh @ h_{t-1}).
// 8 blocks x 512 thr; block owns 64 rows. Thread (i=tid>>4 -> 0..31,
// j=tid&15) owns rows r0=base+2i, r0+1, cols 32j..+31 — 64 W f32 loaded
// VOLATILE (remat of a volatile load is illegal; r13-r15 showed plain loads
// get rematerialized into the t-loop, VGPR stuck at 48).
// Exchange: per-consumer MAILBOXES (out planes 1..4; consumer pairs
// {c, c^4} share plane 1+(c&3)) -> each polled line has <=2 readers instead
// of 7, removing the reader-vs-writer line contention that scales with NBLK
// (r3/r4/r10-vs-r13 evidence). plane0 gets the canonical copy (= hs output,
// unpolled except as fallback).
// Per step: 112 pollers (tid<112) -> ds_write_b128 swizzled; ONE barrier;
// 8 swizzled ds_read_b128 -> 64 FMA (h4 reused across 2 rows) -> 2x red16;
// j==0: 2x tanh, u64 publish to 4 mailboxes + plane0, seed own float2 into
// next LDS buffer.
__global__ __launch_bounds__(512, 2) void recurrence(
    const float* __restrict__ Whh, const float* __restrict__ drive,
    const float* __restrict__ h0, unsigned* __restrict__ plane0,
    unsigned* __restrict__ mail)   // 4 contiguous planes (out planes 1..4)
{
  const size_t PL = (size_t)SEQ * HID;
  const int blk = blockIdx.x;
  const int base = blk * RPB;
  const int tid = threadIdx.x;
  const int i = tid >> 4;        // 0..31
  const int j = tid & 15;        // 0..15
  const int r0 = base + 2 * i;   // first of this thread's two rows

  __shared__ __align__(16) float hbuf[2][HID];

  // W: 2 rows x 32 cols, volatile scalar loads -> non-rematerializable
  float w0[32], w1[32];
  {
    const volatile float* p0 = &Whh[(size_t)r0 * HID + 32 * j];
    const volatile float* p1 = p0 + HID;
#pragma unroll
    for (int c = 0; c < 32; ++c) { w0[c] = p0[c]; w1[c] = p1[c]; }
  }

  // poller mapping: tid<112 -> remote f4 chunk (skip own 16), swizzled slot
  const int ch = (tid < blk * 16) ? tid : tid + 16;   // valid for tid<112
  const int wslot = swz(ch);
  // own-seed slot (j==0): rows r0,r0+1 -> chunk r0>>2, offset r0&3 (0 or 2)
  const int z0 = swz(r0 >> 2) * 4 + (r0 & 3);
  // this consumer's private mailbox plane
  unsigned* mymail = mail + (size_t)(blk & 3) * PL;

  // t=0 seed from h0 (512 threads cover 512 floats exactly)
  hbuf[0][swz(tid >> 2) * 4 + (tid & 3)] = h0[tid];

  for (int t = 0; t < SEQ; ++t) {
    const int buf = t & 1;

    float2 dr = make_float2(0.f, 0.f);
    if (j == 0) dr = *(const float2*)&drive[(size_t)t * HID + r0];

    if (t > 0 && tid < 112) {
      const unsigned* src  = &mymail[(size_t)(t - 1) * HID + 4 * ch];
      const unsigned* safe = &plane0[(size_t)(t - 1) * HID + 4 * ch];
      const uint4 u = poll_chunk(src, safe);
      ((uint4*)hbuf[buf])[wslot] = u;   // one ds_write_b128, swizzled slot
    }
    __syncthreads();   // buf ready; skew <= 1 step => other buffer safe
    asm volatile("" :: "v"(dr.x), "v"(dr.y));   // drv resident by now

    float a00 = 0.f, a01 = 0.f, a02 = 0.f, a03 = 0.f;
    float a10 = 0.f, a11 = 0.f, a12 = 0.f, a13 = 0.f;
#pragma unroll
    for (int c = 0; c < 8; ++c) {
      const float4 h4 = *(const float4*)&hbuf[buf][(8 * j + ((c ^ j) & 7)) * 4];
      a00 = fmaf(w0[4 * c + 0], h4.x, a00);
      a01 = fmaf(w0[4 * c + 1], h4.y, a01);
      a02 = fmaf(w0[4 * c + 2], h4.z, a02);
      a03 = fmaf(w0[4 * c + 3], h4.w, a03);
      a10 = fmaf(w1[4 * c + 0], h4.x, a10);
      a11 = fmaf(w1[4 * c + 1], h4.y, a11);
      a12 = fmaf(w1[4 * c + 2], h4.z, a12);
      a13 = fmaf(w1[4 * c + 3], h4.w, a13);
    }
    float s0 = red16((a00 + a01) + (a02 + a03));
    float s1 = red16((a10 + a11) + (a12 + a13));

    if (j == 0) {
      const float y0 = tanh_fast(s0 + dr.x);
      const float y1 = tanh_fast(s1 + dr.y);
      const u64 pk = (u64)__float_as_uint(y0) | ((u64)__float_as_uint(y1) << 32);
      const size_t off = (size_t)t * HID + r0;
      // mailboxes first (latency-critical: each line has <=2 pollers)
#pragma unroll
      for (int m = 0; m < NMAIL; ++m)
        __hip_atomic_store((u64*)&mail[m * PL + off], pk,
                           __ATOMIC_RELAXED, __HIP_MEMORY_SCOPE_AGENT);
      // canonical copy = hs output (also the poll fallback target)
      __hip_atomic_store((u64*)&plane0[off], pk,
                         __ATOMIC_RELAXED, __HIP_MEMORY_SCOPE_AGENT);
      // own rows never leave the CU: seed next LDS buffer directly.
      *(float2*)&hbuf[buf ^ 1][z0] = make_float2(y0, y1);
    }
  }
}

__global__ void copy_final(const float* __restrict__ src, float* __restrict__ dst) {
  dst[threadIdx.x] = src[threadIdx.x];
}

extern "C" void kernel_launch(void* const* d_in, const int* in_sizes, int n_in,
                              void* d_out, int out_size, void* d_ws, size_t ws_size,
                              hipStream_t stream) {
  const float* input    = (const float*)d_in[0];
  const float* internal = (const float*)d_in[1];
  const float* state    = (const float*)d_in[2];
  const float* W_ih     = (const float*)d_in[3];
  const float* W_hh     = (const float*)d_in[4];
  const float* bias     = (const float*)d_in[5];
  float* out = (float*)d_out;

  const size_t plane = (size_t)SEQ * HID;
  // plane 0 = hs output (canonical publish); planes 1..4 = mailboxes
  // (rewritten by theta GEMMs k=0..3 afterwards); plane 5 = drive
  // (rewritten by theta GEMM k=4 afterwards). All stream-ordered-safe.
  unsigned* plane0 = (unsigned*)out;
  unsigned* mail   = (unsigned*)(out + plane);
  float*    drive  = out + 5 * plane;

  // sentinel planes 0..4
  fill_sentinel<<<((int)(5 * plane / 4) + 255) / 256, 256, 0, stream>>>(
      (uint4*)out, (int)(5 * plane / 4));

  dim3 gg(HID / 64, SEQ / 64);
  // drive = x @ W_ih^T + b + internal[0]   (no tanh)
  gemm_bias_noise<<<gg, 256, 0, stream>>>(input, W_ih, bias, internal, drive,
                                          HID, 0);
  // hs (plane 0) via mailbox sentinel exchange
  recurrence<<<NBLK, 512, 0, stream>>>(W_hh, drive, state, plane0, mail);
  // theta rollouts: plane k -> plane k+1
  for (int k = 0; k < NTHETA; ++k) {
    gemm_bias_noise<<<gg, 256, 0, stream>>>(out + (size_t)k * plane, W_hh, bias,
                                            internal + (size_t)(k + 1) * plane,
                                            out + (size_t)(k + 1) * plane,
                                            HID, 1);
  }
  // final_state = hs[4095]
  copy_final<<<1, HID, 0, stream>>>(out + (size_t)4095 * HID, out + 6 * plane);
}